// Round 10
// baseline (133.206 us; speedup 1.0000x reference)
//
#include <hip/hip_runtime.h>

#define N_NODES    50000
#define N_EDGES    625000
#define HIDDEN     128
#define NUM_GRAPHS 128
#define EPS_GN     1e-5f
#define FIXSCALE   1048576.0f   // 2^20 fixed point for degree accumulation
#define NGEMM_BLK  782          // (N_NODES + 63) / 64
#define NHIST_BLK  1221         // ceil(N_EDGES/2/256)
#define CPAD       8            // counters padded to one per 64B cacheline

typedef __bf16 bf16x8 __attribute__((ext_vector_type(8)));
typedef float  f32x4  __attribute__((ext_vector_type(4)));
typedef unsigned short u16x8 __attribute__((ext_vector_type(8)));
typedef unsigned long long u64;

__device__ inline unsigned short f2b(float f) {
    __bf16 b = (__bf16)f;
    return __builtin_bit_cast(unsigned short, b);
}
__device__ inline float b2f(unsigned short u) {
    unsigned int x = ((unsigned int)u) << 16;
    return __builtin_bit_cast(float, x);
}

// ---- workspace layout (4B units; u64 regions at even offsets) ----
#define HB_OFF     0          // ushort[6,400,000] bf16(h)   -> 3,200,000 units
#define CNT64_OFF  3200000    // u64[50,000 * 8] padded      -> 800,000 units
#define DINV_OFF   4000000    // float[50,000]
#define SCALE_OFF  4050000    // float[16,384]
#define SHIFT_OFF  4066384    // float[16,384]
#define GSTART_OFF 4082768    // int[129]
#define ROWS_OFF   4083000    // int[50,001]
#define BSUM_OFF   4133100    // int[256]
#define BOFF_OFF   4133400    // int[256]
#define EPACK_OFF  4133700    // u64[625,000]                -> 1,250,000 units (even)
#define SLOT_OFF   5383700    // u32[625,000]
#define WB_OFF     6008700    // ushort[16,384] bf16(W)      -> 8,192 units

// ---------------- prep: zero padded cnt64 region + convert W -> bf16 ----------------
__global__ void prep(const float* __restrict__ W, unsigned short* __restrict__ wb,
                     uint4* __restrict__ cntz) {
    int i = blockIdx.x * 256 + threadIdx.x;
    if (i < 800000 / 4) cntz[i] = make_uint4(0u, 0u, 0u, 0u);
    if (i < HIDDEN * HIDDEN) wb[i] = f2b(W[i]);
}

// ---------------- fused: GEMM tiles (blocks < NGEMM_BLK) + edge histogram ----------------
__global__ __launch_bounds__(256) void gemm_hist(const float* __restrict__ x,
                                                 const unsigned short* __restrict__ wb,
                                                 unsigned short* __restrict__ hb,
                                                 const int* __restrict__ dst,
                                                 const float* __restrict__ w,
                                                 u64* __restrict__ cnt64,
                                                 unsigned int* __restrict__ slot) {
    if (blockIdx.x >= NGEMM_BLK) {
        // ---- histogram part: 2 edges/thread, padded counters ----
        int base = (blockIdx.x - NGEMM_BLK) * 256 + threadIdx.x;
        if (base * 2 >= N_EDGES) return;
        int2   d2 = ((const int2*)dst)[base];
        float2 w2 = ((const float2*)w)[base];
        unsigned int fx0 = (unsigned int)(w2.x * FIXSCALE + 0.5f);
        unsigned int fx1 = (unsigned int)(w2.y * FIXSCALE + 0.5f);
        u64 o0 = atomicAdd(&cnt64[(size_t)d2.x * CPAD], (1ULL << 32) | (u64)fx0);
        u64 o1 = atomicAdd(&cnt64[(size_t)d2.y * CPAD], (1ULL << 32) | (u64)fx1);
        uint2 s2;
        s2.x = (unsigned int)(o0 >> 32);
        s2.y = (unsigned int)(o1 >> 32);
        ((uint2*)slot)[base] = s2;
        return;
    }
    // ---- GEMM part: h = x @ W.T, all A-loads hoisted ----
    const int wave = threadIdx.x >> 6;
    const int lane = threadIdx.x & 63;
    const int row0 = blockIdx.x * 64 + wave * 16;
    const int r  = lane & 15;
    const int ko = (lane >> 4) * 8;
    int arow = row0 + r;
    if (arow >= N_NODES) arow = N_NODES - 1;
    const size_t abase = (size_t)arow * HIDDEN + ko;

    // issue all 8 independent A loads up front (full K slice for this lane)
    float4 a0[4], a1[4];
#pragma unroll
    for (int k4 = 0; k4 < 4; ++k4) {
        a0[k4] = *(const float4*)(x + abase + k4 * 32);
        a1[k4] = *(const float4*)(x + abase + k4 * 32 + 4);
    }
    bf16x8 a[4];
#pragma unroll
    for (int k4 = 0; k4 < 4; ++k4) {
        a[k4][0] = (__bf16)a0[k4].x; a[k4][1] = (__bf16)a0[k4].y;
        a[k4][2] = (__bf16)a0[k4].z; a[k4][3] = (__bf16)a0[k4].w;
        a[k4][4] = (__bf16)a1[k4].x; a[k4][5] = (__bf16)a1[k4].y;
        a[k4][6] = (__bf16)a1[k4].z; a[k4][7] = (__bf16)a1[k4].w;
    }
    f32x4 acc[8];
#pragma unroll
    for (int t = 0; t < 8; ++t) { acc[t][0] = 0.f; acc[t][1] = 0.f; acc[t][2] = 0.f; acc[t][3] = 0.f; }
#pragma unroll
    for (int k4 = 0; k4 < 4; ++k4) {
#pragma unroll
        for (int t = 0; t < 8; ++t) {
            bf16x8 b = *(const bf16x8*)(wb + (size_t)(t * 16 + r) * HIDDEN + k4 * 32 + ko);
            acc[t] = __builtin_amdgcn_mfma_f32_16x16x32_bf16(a[k4], b, acc[t], 0, 0, 0);
        }
    }
    const int orow = row0 + (lane >> 4) * 4;
#pragma unroll
    for (int t = 0; t < 8; ++t) {
#pragma unroll
        for (int j = 0; j < 4; ++j) {
            int rr = orow + j;
            if (rr < N_NODES) hb[(size_t)rr * HIDDEN + t * 16 + r] = f2b(acc[t][j]);
        }
    }
}

// ---------------- scan partials + dinv + graph bounds (fused) ----------------
__global__ void scan_partial(const u64* __restrict__ cnt64, int* __restrict__ bsum,
                             float* __restrict__ dinv,
                             const int* __restrict__ batch, int* __restrict__ gstart) {
    __shared__ int red[256];
    int i = blockIdx.x * 256 + threadIdx.x;
    int c = 0;
    if (i < N_NODES) {
        u64 v = cnt64[(size_t)i * CPAD];
        c = (int)(v >> 32);
        dinv[i] = rsqrtf(1.0f + (float)(unsigned int)v * (1.0f / FIXSCALE));
        int b0 = batch[i];
        int prev = (i == 0) ? -1 : batch[i - 1];
        for (int g = prev + 1; g <= b0; ++g) gstart[g] = i;
        if (i == N_NODES - 1) {
            for (int g = b0 + 1; g <= NUM_GRAPHS; ++g) gstart[g] = N_NODES;
        }
    }
    red[threadIdx.x] = c;
    __syncthreads();
    for (int off = 128; off > 0; off >>= 1) {
        if (threadIdx.x < off) red[threadIdx.x] += red[threadIdx.x + off];
        __syncthreads();
    }
    if (threadIdx.x == 0) bsum[blockIdx.x] = red[0];
}

__global__ void scan_bsums(const int* __restrict__ bsum, int* __restrict__ boff, int nblocks) {
    __shared__ int s[256];
    int t = threadIdx.x;
    int v0 = (t < nblocks) ? bsum[t] : 0;
    s[t] = v0;
    __syncthreads();
    for (int off = 1; off < 256; off <<= 1) {
        int v = (t >= off) ? s[t - off] : 0;
        __syncthreads();
        s[t] += v;
        __syncthreads();
    }
    boff[t] = s[t] - v0;   // exclusive
}

__global__ void scan_emit(const u64* __restrict__ cnt64, const int* __restrict__ boff,
                          int* __restrict__ rowstart) {
    __shared__ int s[256];
    int t = threadIdx.x;
    int i = blockIdx.x * 256 + t;
    int v0 = (i < N_NODES) ? (int)(cnt64[(size_t)i * CPAD] >> 32) : 0;
    s[t] = v0;
    __syncthreads();
    for (int off = 1; off < 256; off <<= 1) {
        int v = (t >= off) ? s[t - off] : 0;
        __syncthreads();
        s[t] += v;
        __syncthreads();
    }
    if (i < N_NODES) rowstart[i] = boff[blockIdx.x] + s[t] - v0;
    if (i == N_NODES) rowstart[N_NODES] = N_EDGES;
}

// ---------------- fill CSR: atomic-free, 4 edges/thread ----------------
__global__ void csr_fill(const int* __restrict__ src, const int* __restrict__ dst,
                         const float* __restrict__ w, const float* __restrict__ dinv,
                         const int* __restrict__ rowstart, const unsigned int* __restrict__ slot,
                         u64* __restrict__ epack) {
    int base = blockIdx.x * blockDim.x + threadIdx.x;
    if (base * 4 >= N_EDGES) return;
    int4   s4 = ((const int4*)src)[base];
    int4   d4 = ((const int4*)dst)[base];
    float4 w4 = ((const float4*)w)[base];
    uint4  r4 = ((const uint4*)slot)[base];
    float nm0 = dinv[s4.x] * w4.x * dinv[d4.x];
    float nm1 = dinv[s4.y] * w4.y * dinv[d4.y];
    float nm2 = dinv[s4.z] * w4.z * dinv[d4.z];
    float nm3 = dinv[s4.w] * w4.w * dinv[d4.w];
    epack[rowstart[d4.x] + (int)r4.x] = (u64)(unsigned int)s4.x | ((u64)__float_as_uint(nm0) << 32);
    epack[rowstart[d4.y] + (int)r4.y] = (u64)(unsigned int)s4.y | ((u64)__float_as_uint(nm1) << 32);
    epack[rowstart[d4.z] + (int)r4.z] = (u64)(unsigned int)s4.z | ((u64)__float_as_uint(nm2) << 32);
    epack[rowstart[d4.w] + (int)r4.w] = (u64)(unsigned int)s4.w | ((u64)__float_as_uint(nm3) << 32);
}

// ---------------- gather: 16 lanes/node, 16B row loads ----------------
__global__ __launch_bounds__(256) void gather_fused(const unsigned short* __restrict__ hb,
                                                    const int* __restrict__ rowstart,
                                                    const u64* __restrict__ epack,
                                                    const float* __restrict__ dinv,
                                                    const float* __restrict__ b,
                                                    float* __restrict__ out) {
    const int t = threadIdx.x;
    const int n = blockIdx.x * 16 + (t >> 4);
    if (n >= N_NODES) return;
    const int c8 = (t & 15) * 8;
    const int s0 = rowstart[n];
    const int e0 = rowstart[n + 1];
    const float di = dinv[n];
    const float sl = di * di;
    float acc[8];
    {
        u16x8 hv = *(const u16x8*)(hb + (size_t)n * HIDDEN + c8);
#pragma unroll
        for (int j = 0; j < 8; ++j) acc[j] = sl * b2f(hv[j]);
    }
    int p = s0;
    for (; p + 2 <= e0; p += 2) {
        u64 e1 = epack[p];
        u64 e2 = epack[p + 1];
        int   s1 = (int)(unsigned int)e1;
        float n1 = __uint_as_float((unsigned int)(e1 >> 32));
        int   sg2 = (int)(unsigned int)e2;
        float n2 = __uint_as_float((unsigned int)(e2 >> 32));
        u16x8 v1 = *(const u16x8*)(hb + (size_t)s1 * HIDDEN + c8);
        u16x8 v2 = *(const u16x8*)(hb + (size_t)sg2 * HIDDEN + c8);
#pragma unroll
        for (int j = 0; j < 8; ++j) acc[j] = fmaf(n1, b2f(v1[j]), acc[j]);
#pragma unroll
        for (int j = 0; j < 8; ++j) acc[j] = fmaf(n2, b2f(v2[j]), acc[j]);
    }
    if (p < e0) {
        u64 e1 = epack[p];
        int   s1 = (int)(unsigned int)e1;
        float n1 = __uint_as_float((unsigned int)(e1 >> 32));
        u16x8 v1 = *(const u16x8*)(hb + (size_t)s1 * HIDDEN + c8);
#pragma unroll
        for (int j = 0; j < 8; ++j) acc[j] = fmaf(n1, b2f(v1[j]), acc[j]);
    }
    float4 b0 = *(const float4*)(b + c8);
    float4 b1 = *(const float4*)(b + c8 + 4);
    float4 o0, o1;
    o0.x = acc[0] + b0.x; o0.y = acc[1] + b0.y; o0.z = acc[2] + b0.z; o0.w = acc[3] + b0.w;
    o1.x = acc[4] + b1.x; o1.y = acc[5] + b1.y; o1.z = acc[6] + b1.z; o1.w = acc[7] + b1.w;
    *(float4*)(out + (size_t)n * HIDDEN + c8)     = o0;
    *(float4*)(out + (size_t)n * HIDDEN + c8 + 4) = o1;
}

// ---------------- per-graph stats -> scale/shift ----------------
__global__ __launch_bounds__(256) void graph_stats(const float* __restrict__ out,
                                                   const int* __restrict__ gstart,
                                                   const float* __restrict__ ms,
                                                   const float* __restrict__ gw,
                                                   const float* __restrict__ gb,
                                                   float* __restrict__ scale,
                                                   float* __restrict__ shift) {
    const int g = blockIdx.x >> 2;
    const int q = blockIdx.x & 3;
    const int c = q * 32 + (threadIdx.x & 31);
    const int r = threadIdx.x >> 5;
    const int s = gstart[g];
    const int e = gstart[g + 1];
    float sum = 0.f, sq = 0.f;
    for (int n = s + r; n < e; n += 8) {
        float v = out[(size_t)n * HIDDEN + c];
        sum += v;
        sq = fmaf(v, v, sq);
    }
    __shared__ float ssum[8][32], ssq[8][32];
    ssum[r][threadIdx.x & 31] = sum;
    ssq[r][threadIdx.x & 31]  = sq;
    __syncthreads();
    if (r == 0) {
        int l = threadIdx.x & 31;
#pragma unroll
        for (int i = 1; i < 8; ++i) { sum += ssum[i][l]; sq += ssq[i][l]; }
        float cnt  = (float)max(e - s, 1);
        float mean = sum / cnt;
        float m2   = sq / cnt;
        float msv  = ms[c];
        float var  = fmaxf(m2 - mean * mean * msv * (2.f - msv), 0.f);
        float a    = gw[c] * rsqrtf(var + EPS_GN);
        scale[g * HIDDEN + c] = a;
        shift[g * HIDDEN + c] = gb[c] - a * msv * mean;
    }
}

// ---------------- normalize + affine + relu ----------------
__global__ __launch_bounds__(256) void gn_final(float* __restrict__ out,
                                                const float* __restrict__ scale,
                                                const float* __restrict__ shift,
                                                const int* __restrict__ batch) {
    int idx = blockIdx.x * blockDim.x + threadIdx.x;
    if (idx >= N_NODES * 32) return;
    int n  = idx >> 5;
    int c4 = (idx & 31) * 4;
    int g  = batch[n];
    float4 v  = *(float4*)(out + (size_t)n * HIDDEN + c4);
    float4 a  = *(const float4*)(scale + (size_t)g * HIDDEN + c4);
    float4 s  = *(const float4*)(shift + (size_t)g * HIDDEN + c4);
    v.x = fmaxf(fmaf(a.x, v.x, s.x), 0.f);
    v.y = fmaxf(fmaf(a.y, v.y, s.y), 0.f);
    v.z = fmaxf(fmaf(a.z, v.z, s.z), 0.f);
    v.w = fmaxf(fmaf(a.w, v.w, s.w), 0.f);
    *(float4*)(out + (size_t)n * HIDDEN + c4) = v;
}

extern "C" void kernel_launch(void* const* d_in, const int* in_sizes, int n_in,
                              void* d_out, int out_size, void* d_ws, size_t ws_size,
                              hipStream_t stream) {
    const float* node  = (const float*)d_in[0];
    const int*   ei    = (const int*)d_in[1];
    const float* eattr = (const float*)d_in[2];
    const int*   batch = (const int*)d_in[3];
    const float* W     = (const float*)d_in[4];
    const float* b     = (const float*)d_in[5];
    const float* gnw   = (const float*)d_in[6];
    const float* gnb   = (const float*)d_in[7];
    const float* gnms  = (const float*)d_in[8];
    float* out = (float*)d_out;
    float* ws  = (float*)d_ws;

    const int* src = ei;
    const int* dst = ei + N_EDGES;

    unsigned short* hb = (unsigned short*)(ws + HB_OFF);
    u64*   cnt64   = (u64*)(ws + CNT64_OFF);
    float* dinv    = ws + DINV_OFF;
    float* scale   = ws + SCALE_OFF;
    float* shift   = ws + SHIFT_OFF;
    int*   gstart  = (int*)(ws + GSTART_OFF);
    int*   rowstart= (int*)(ws + ROWS_OFF);
    int*   bsum    = (int*)(ws + BSUM_OFF);
    int*   boff    = (int*)(ws + BOFF_OFF);
    u64*   epack   = (u64*)(ws + EPACK_OFF);
    unsigned int* slot = (unsigned int*)(ws + SLOT_OFF);
    unsigned short* wb = (unsigned short*)(ws + WB_OFF);

    const int NB = (N_NODES + 255) / 256;   // 196

    prep<<<(200000 + 255) / 256, 256, 0, stream>>>(W, wb, (uint4*)cnt64);
    gemm_hist<<<NGEMM_BLK + NHIST_BLK, 256, 0, stream>>>(node, wb, hb, dst, eattr, cnt64, slot);
    scan_partial<<<NB, 256, 0, stream>>>(cnt64, bsum, dinv, batch, gstart);
    scan_bsums<<<1, 256, 0, stream>>>(bsum, boff, NB);
    scan_emit<<<NB, 256, 0, stream>>>(cnt64, boff, rowstart);
    csr_fill<<<(N_EDGES / 4 + 255) / 256, 256, 0, stream>>>(src, dst, eattr, dinv, rowstart, slot, epack);
    gather_fused<<<(N_NODES + 15) / 16, 256, 0, stream>>>(hb, rowstart, epack, dinv, b, out);
    graph_stats<<<NUM_GRAPHS * 4, 256, 0, stream>>>(out, gstart, gnms, gnw, gnb, scale, shift);
    gn_final<<<(N_NODES * 32 + 255) / 256, 256, 0, stream>>>(out, scale, shift, batch);

    (void)in_sizes; (void)n_in; (void)out_size; (void)ws_size;
}

// Round 11
// 128.290 us; speedup vs baseline: 1.0383x; 1.0383x over previous
//
#include <hip/hip_runtime.h>

#define N_NODES    50000
#define N_EDGES    625000
#define HIDDEN     128
#define NUM_GRAPHS 128
#define EPS_GN     1e-5f
#define FIXSCALE   1048576.0f   // 2^20 fixed point for degree accumulation
#define NGEMM_BLK  782          // (N_NODES + 63) / 64
#define NHIST_BLK  611          // ceil(N_EDGES/4/256)
#define CPAD       8            // counters padded to one per 64B cacheline

typedef __bf16 bf16x8 __attribute__((ext_vector_type(8)));
typedef float  f32x4  __attribute__((ext_vector_type(4)));
typedef unsigned short u16x8 __attribute__((ext_vector_type(8)));
typedef unsigned long long u64;

__device__ inline unsigned short f2b(float f) {
    __bf16 b = (__bf16)f;
    return __builtin_bit_cast(unsigned short, b);
}
__device__ inline float b2f(unsigned short u) {
    unsigned int x = ((unsigned int)u) << 16;
    return __builtin_bit_cast(float, x);
}

// ---- workspace layout (4B units; u64 regions at even offsets) ----
#define HB_OFF     0          // ushort[6,400,000] bf16(h)   -> 3,200,000 units
#define CNT64_OFF  3200000    // u64[50,000 * 8] padded      -> 800,000 units
#define DINV_OFF   4000000    // float[50,000]
#define GSTART_OFF 4082768    // int[129]
#define ROWS_OFF   4083000    // int[50,001]
#define BSUM_OFF   4133100    // int[256]
#define BOFF_OFF   4133400    // int[256]
#define EPACK_OFF  4133700    // u64[625,000]                -> 1,250,000 units (even)
#define SLOT_OFF   5383700    // u32[625,000]
#define WB_OFF     6008700    // ushort[16,384] bf16(W)      -> 8,192 units
#define TMP_OFF    6020000    // ushort[6,400,000] bf16 pre-norm -> 3,200,000 units
// end 9,220,000 * 4B = 36.9 MB?  -> too big? previous max used 31.4MB fine; trim:
// reuse SLOT region? slot is consumed by csr_fill before gather runs -> overlay TMP on SLOT+WB tail:
#undef TMP_OFF
#define TMP_OFF    5383700    // overlays SLOT (u32[625,000]=625,000 units) + extra; slot dead after csr_fill
// TMP needs 1,600,000 units -> [5,383,700 , 6,983,700); WB at 6,008,700 would collide ->
// move WB before EPACK instead:
#undef WB_OFF
#define WB_OFF     4050000    // ushort[16,384] in the gap after DINV (4,000,000+12,500=4,012,500 < 4,050,000; ends 4,058,192 < GSTART 4,082,768)
// final extent: TMP end 6,983,700 units = 27.9 MB

// ---------------- prep: zero padded cnt64 region + convert W -> bf16 ----------------
__global__ void prep(const float* __restrict__ W, unsigned short* __restrict__ wb,
                     uint4* __restrict__ cntz) {
    int i = blockIdx.x * 256 + threadIdx.x;
    if (i < 800000 / 4) cntz[i] = make_uint4(0u, 0u, 0u, 0u);
    if (i < HIDDEN * HIDDEN) wb[i] = f2b(W[i]);
}

// ---------------- fused: GEMM tiles (blocks < NGEMM_BLK) + edge histogram ----------------
__global__ __launch_bounds__(256) void gemm_hist(const float* __restrict__ x,
                                                 const unsigned short* __restrict__ wb,
                                                 unsigned short* __restrict__ hb,
                                                 const int* __restrict__ dst,
                                                 const float* __restrict__ w,
                                                 u64* __restrict__ cnt64,
                                                 unsigned int* __restrict__ slot) {
    if (blockIdx.x >= NGEMM_BLK) {
        // ---- histogram part: 4 edges/thread, padded counters ----
        int base = (blockIdx.x - NGEMM_BLK) * 256 + threadIdx.x;
        if (base * 4 >= N_EDGES) return;
        int4   d4 = ((const int4*)dst)[base];
        float4 w4 = ((const float4*)w)[base];
        unsigned int fx0 = (unsigned int)(w4.x * FIXSCALE + 0.5f);
        unsigned int fx1 = (unsigned int)(w4.y * FIXSCALE + 0.5f);
        unsigned int fx2 = (unsigned int)(w4.z * FIXSCALE + 0.5f);
        unsigned int fx3 = (unsigned int)(w4.w * FIXSCALE + 0.5f);
        u64 o0 = atomicAdd(&cnt64[(size_t)d4.x * CPAD], (1ULL << 32) | (u64)fx0);
        u64 o1 = atomicAdd(&cnt64[(size_t)d4.y * CPAD], (1ULL << 32) | (u64)fx1);
        u64 o2 = atomicAdd(&cnt64[(size_t)d4.z * CPAD], (1ULL << 32) | (u64)fx2);
        u64 o3 = atomicAdd(&cnt64[(size_t)d4.w * CPAD], (1ULL << 32) | (u64)fx3);
        uint4 s4;
        s4.x = (unsigned int)(o0 >> 32);
        s4.y = (unsigned int)(o1 >> 32);
        s4.z = (unsigned int)(o2 >> 32);
        s4.w = (unsigned int)(o3 >> 32);
        ((uint4*)slot)[base] = s4;
        return;
    }
    // ---- GEMM part: h = x @ W.T (R8 structure: loads interleaved in k-loop) ----
    const int wave = threadIdx.x >> 6;
    const int lane = threadIdx.x & 63;
    const int row0 = blockIdx.x * 64 + wave * 16;
    const int r  = lane & 15;
    const int ko = (lane >> 4) * 8;
    f32x4 acc[8];
#pragma unroll
    for (int t = 0; t < 8; ++t) { acc[t][0] = 0.f; acc[t][1] = 0.f; acc[t][2] = 0.f; acc[t][3] = 0.f; }
    int arow = row0 + r;
    if (arow >= N_NODES) arow = N_NODES - 1;
    const size_t abase = (size_t)arow * HIDDEN + ko;
#pragma unroll
    for (int kt = 0; kt < HIDDEN; kt += 32) {
        float4 a0 = *(const float4*)(x + abase + kt);
        float4 a1 = *(const float4*)(x + abase + kt + 4);
        bf16x8 a;
        a[0] = (__bf16)a0.x; a[1] = (__bf16)a0.y; a[2] = (__bf16)a0.z; a[3] = (__bf16)a0.w;
        a[4] = (__bf16)a1.x; a[5] = (__bf16)a1.y; a[6] = (__bf16)a1.z; a[7] = (__bf16)a1.w;
#pragma unroll
        for (int t = 0; t < 8; ++t) {
            bf16x8 b = *(const bf16x8*)(wb + (size_t)(t * 16 + r) * HIDDEN + kt + ko);
            acc[t] = __builtin_amdgcn_mfma_f32_16x16x32_bf16(a, b, acc[t], 0, 0, 0);
        }
    }
    const int orow = row0 + (lane >> 4) * 4;
#pragma unroll
    for (int t = 0; t < 8; ++t) {
#pragma unroll
        for (int j = 0; j < 4; ++j) {
            int rr = orow + j;
            if (rr < N_NODES) hb[(size_t)rr * HIDDEN + t * 16 + r] = f2b(acc[t][j]);
        }
    }
}

// ---------------- scan partials + dinv + graph bounds (fused) ----------------
__global__ void scan_partial(const u64* __restrict__ cnt64, int* __restrict__ bsum,
                             float* __restrict__ dinv,
                             const int* __restrict__ batch, int* __restrict__ gstart) {
    __shared__ int red[256];
    int i = blockIdx.x * 256 + threadIdx.x;
    int c = 0;
    if (i < N_NODES) {
        u64 v = cnt64[(size_t)i * CPAD];
        c = (int)(v >> 32);
        dinv[i] = rsqrtf(1.0f + (float)(unsigned int)v * (1.0f / FIXSCALE));
        int b0 = batch[i];
        int prev = (i == 0) ? -1 : batch[i - 1];
        for (int g = prev + 1; g <= b0; ++g) gstart[g] = i;
        if (i == N_NODES - 1) {
            for (int g = b0 + 1; g <= NUM_GRAPHS; ++g) gstart[g] = N_NODES;
        }
    }
    red[threadIdx.x] = c;
    __syncthreads();
    for (int off = 128; off > 0; off >>= 1) {
        if (threadIdx.x < off) red[threadIdx.x] += red[threadIdx.x + off];
        __syncthreads();
    }
    if (threadIdx.x == 0) bsum[blockIdx.x] = red[0];
}

__global__ void scan_bsums(const int* __restrict__ bsum, int* __restrict__ boff, int nblocks) {
    __shared__ int s[256];
    int t = threadIdx.x;
    int v0 = (t < nblocks) ? bsum[t] : 0;
    s[t] = v0;
    __syncthreads();
    for (int off = 1; off < 256; off <<= 1) {
        int v = (t >= off) ? s[t - off] : 0;
        __syncthreads();
        s[t] += v;
        __syncthreads();
    }
    boff[t] = s[t] - v0;   // exclusive
}

__global__ void scan_emit(const u64* __restrict__ cnt64, const int* __restrict__ boff,
                          int* __restrict__ rowstart) {
    __shared__ int s[256];
    int t = threadIdx.x;
    int i = blockIdx.x * 256 + t;
    int v0 = (i < N_NODES) ? (int)(cnt64[(size_t)i * CPAD] >> 32) : 0;
    s[t] = v0;
    __syncthreads();
    for (int off = 1; off < 256; off <<= 1) {
        int v = (t >= off) ? s[t - off] : 0;
        __syncthreads();
        s[t] += v;
        __syncthreads();
    }
    if (i < N_NODES) rowstart[i] = boff[blockIdx.x] + s[t] - v0;
    if (i == N_NODES) rowstart[N_NODES] = N_EDGES;
}

// ---------------- fill CSR: atomic-free, 4 edges/thread ----------------
__global__ void csr_fill(const int* __restrict__ src, const int* __restrict__ dst,
                         const float* __restrict__ w, const float* __restrict__ dinv,
                         const int* __restrict__ rowstart, const unsigned int* __restrict__ slot,
                         u64* __restrict__ epack) {
    int base = blockIdx.x * blockDim.x + threadIdx.x;
    if (base * 4 >= N_EDGES) return;
    int4   s4 = ((const int4*)src)[base];
    int4   d4 = ((const int4*)dst)[base];
    float4 w4 = ((const float4*)w)[base];
    uint4  r4 = ((const uint4*)slot)[base];
    float nm0 = dinv[s4.x] * w4.x * dinv[d4.x];
    float nm1 = dinv[s4.y] * w4.y * dinv[d4.y];
    float nm2 = dinv[s4.z] * w4.z * dinv[d4.z];
    float nm3 = dinv[s4.w] * w4.w * dinv[d4.w];
    epack[rowstart[d4.x] + (int)r4.x] = (u64)(unsigned int)s4.x | ((u64)__float_as_uint(nm0) << 32);
    epack[rowstart[d4.y] + (int)r4.y] = (u64)(unsigned int)s4.y | ((u64)__float_as_uint(nm1) << 32);
    epack[rowstart[d4.z] + (int)r4.z] = (u64)(unsigned int)s4.z | ((u64)__float_as_uint(nm2) << 32);
    epack[rowstart[d4.w] + (int)r4.w] = (u64)(unsigned int)s4.w | ((u64)__float_as_uint(nm3) << 32);
}

// ---------------- gather: 16 lanes/node, 16B row loads; writes bf16 tmp ----------------
__global__ __launch_bounds__(256) void gather_fused(const unsigned short* __restrict__ hb,
                                                    const int* __restrict__ rowstart,
                                                    const u64* __restrict__ epack,
                                                    const float* __restrict__ dinv,
                                                    const float* __restrict__ b,
                                                    unsigned short* __restrict__ tmp) {
    const int t = threadIdx.x;
    const int n = blockIdx.x * 16 + (t >> 4);
    if (n >= N_NODES) return;
    const int c8 = (t & 15) * 8;
    const int s0 = rowstart[n];
    const int e0 = rowstart[n + 1];
    const float di = dinv[n];
    const float sl = di * di;
    float acc[8];
    {
        u16x8 hv = *(const u16x8*)(hb + (size_t)n * HIDDEN + c8);
#pragma unroll
        for (int j = 0; j < 8; ++j) acc[j] = sl * b2f(hv[j]);
    }
    int p = s0;
    for (; p + 2 <= e0; p += 2) {
        u64 e1 = epack[p];
        u64 e2 = epack[p + 1];
        int   s1 = (int)(unsigned int)e1;
        float n1 = __uint_as_float((unsigned int)(e1 >> 32));
        int   sg2 = (int)(unsigned int)e2;
        float n2 = __uint_as_float((unsigned int)(e2 >> 32));
        u16x8 v1 = *(const u16x8*)(hb + (size_t)s1 * HIDDEN + c8);
        u16x8 v2 = *(const u16x8*)(hb + (size_t)sg2 * HIDDEN + c8);
#pragma unroll
        for (int j = 0; j < 8; ++j) acc[j] = fmaf(n1, b2f(v1[j]), acc[j]);
#pragma unroll
        for (int j = 0; j < 8; ++j) acc[j] = fmaf(n2, b2f(v2[j]), acc[j]);
    }
    if (p < e0) {
        u64 e1 = epack[p];
        int   s1 = (int)(unsigned int)e1;
        float n1 = __uint_as_float((unsigned int)(e1 >> 32));
        u16x8 v1 = *(const u16x8*)(hb + (size_t)s1 * HIDDEN + c8);
#pragma unroll
        for (int j = 0; j < 8; ++j) acc[j] = fmaf(n1, b2f(v1[j]), acc[j]);
    }
    float4 b0 = *(const float4*)(b + c8);
    float4 b1 = *(const float4*)(b + c8 + 4);
    u16x8 o;
    o[0] = f2b(acc[0] + b0.x); o[1] = f2b(acc[1] + b0.y);
    o[2] = f2b(acc[2] + b0.z); o[3] = f2b(acc[3] + b0.w);
    o[4] = f2b(acc[4] + b1.x); o[5] = f2b(acc[5] + b1.y);
    o[6] = f2b(acc[6] + b1.z); o[7] = f2b(acc[7] + b1.w);
    *(u16x8*)(tmp + (size_t)n * HIDDEN + c8) = o;
}

// ---------------- fused per-graph stats + normalize + relu ----------------
__global__ __launch_bounds__(256) void stats_apply(const unsigned short* __restrict__ tmp,
                                                   const int* __restrict__ gstart,
                                                   const float* __restrict__ ms,
                                                   const float* __restrict__ gw,
                                                   const float* __restrict__ gb,
                                                   float* __restrict__ out) {
    const int g = blockIdx.x >> 2;
    const int q = blockIdx.x & 3;
    const int l = threadIdx.x & 31;
    const int c = q * 32 + l;
    const int r = threadIdx.x >> 5;
    const int s = gstart[g];
    const int e = gstart[g + 1];
    float sum = 0.f, sq = 0.f;
    for (int n = s + r; n < e; n += 8) {
        float v = b2f(tmp[(size_t)n * HIDDEN + c]);
        sum += v;
        sq = fmaf(v, v, sq);
    }
    __shared__ float ssum[8][32], ssq[8][32];
    __shared__ float sA[32], sS[32];
    ssum[r][l] = sum;
    ssq[r][l]  = sq;
    __syncthreads();
    if (r == 0) {
#pragma unroll
        for (int i = 1; i < 8; ++i) { sum += ssum[i][l]; sq += ssq[i][l]; }
        float cnt  = (float)max(e - s, 1);
        float mean = sum / cnt;
        float m2   = sq / cnt;
        float msv  = ms[c];
        float var  = fmaxf(m2 - mean * mean * msv * (2.f - msv), 0.f);
        float a    = gw[c] * rsqrtf(var + EPS_GN);
        sA[l] = a;
        sS[l] = gb[c] - a * msv * mean;
    }
    __syncthreads();
    float a  = sA[l];
    float sh = sS[l];
    for (int n = s + r; n < e; n += 8) {
        float v = b2f(tmp[(size_t)n * HIDDEN + c]);
        out[(size_t)n * HIDDEN + c] = fmaxf(fmaf(a, v, sh), 0.f);
    }
}

extern "C" void kernel_launch(void* const* d_in, const int* in_sizes, int n_in,
                              void* d_out, int out_size, void* d_ws, size_t ws_size,
                              hipStream_t stream) {
    const float* node  = (const float*)d_in[0];
    const int*   ei    = (const int*)d_in[1];
    const float* eattr = (const float*)d_in[2];
    const int*   batch = (const int*)d_in[3];
    const float* W     = (const float*)d_in[4];
    const float* b     = (const float*)d_in[5];
    const float* gnw   = (const float*)d_in[6];
    const float* gnb   = (const float*)d_in[7];
    const float* gnms  = (const float*)d_in[8];
    float* out = (float*)d_out;
    float* ws  = (float*)d_ws;

    const int* src = ei;
    const int* dst = ei + N_EDGES;

    unsigned short* hb = (unsigned short*)(ws + HB_OFF);
    u64*   cnt64   = (u64*)(ws + CNT64_OFF);
    float* dinv    = ws + DINV_OFF;
    int*   gstart  = (int*)(ws + GSTART_OFF);
    int*   rowstart= (int*)(ws + ROWS_OFF);
    int*   bsum    = (int*)(ws + BSUM_OFF);
    int*   boff    = (int*)(ws + BOFF_OFF);
    u64*   epack   = (u64*)(ws + EPACK_OFF);
    unsigned int* slot = (unsigned int*)(ws + SLOT_OFF);
    unsigned short* wb = (unsigned short*)(ws + WB_OFF);
    unsigned short* tmp = (unsigned short*)(ws + TMP_OFF);   // overlays slot (dead after csr_fill)

    const int NB = (N_NODES + 255) / 256;   // 196

    prep<<<(200000 + 255) / 256, 256, 0, stream>>>(W, wb, (uint4*)cnt64);
    gemm_hist<<<NGEMM_BLK + NHIST_BLK, 256, 0, stream>>>(node, wb, hb, dst, eattr, cnt64, slot);
    scan_partial<<<NB, 256, 0, stream>>>(cnt64, bsum, dinv, batch, gstart);
    scan_bsums<<<1, 256, 0, stream>>>(bsum, boff, NB);
    scan_emit<<<NB, 256, 0, stream>>>(cnt64, boff, rowstart);
    csr_fill<<<(N_EDGES / 4 + 255) / 256, 256, 0, stream>>>(src, dst, eattr, dinv, rowstart, slot, epack);
    gather_fused<<<(N_NODES + 15) / 16, 256, 0, stream>>>(hb, rowstart, epack, dinv, b, tmp);
    stats_apply<<<NUM_GRAPHS * 4, 256, 0, stream>>>(tmp, gstart, gnms, gnw, gnb, out);

    (void)in_sizes; (void)n_in; (void)out_size; (void)ws_size;
}

// Round 12
// 124.485 us; speedup vs baseline: 1.0701x; 1.0306x over previous
//
#include <hip/hip_runtime.h>

#define N_NODES    50000
#define N_EDGES    625000
#define HIDDEN     128
#define NUM_GRAPHS 128
#define EPS_GN     1e-5f
#define FIXSCALE   1048576.0f   // 2^20 fixed point for degree accumulation
#define NGEMM_BLK  782          // (N_NODES + 63) / 64
#define NHIST_BLK  306          // ceil(N_EDGES/8/256)
#define NB_SCAN    196          // ceil(N_NODES/256)

typedef __bf16 bf16x8 __attribute__((ext_vector_type(8)));
typedef float  f32x4  __attribute__((ext_vector_type(4)));
typedef unsigned short u16x8 __attribute__((ext_vector_type(8)));
typedef unsigned long long u64;

__device__ inline unsigned short f2b(float f) {
    __bf16 b = (__bf16)f;
    return __builtin_bit_cast(unsigned short, b);
}
__device__ inline float b2f(unsigned short u) {
    unsigned int x = ((unsigned int)u) << 16;
    return __builtin_bit_cast(float, x);
}

// ---- workspace layout (4B units) ----
#define HB_OFF     0          // ushort[6,400,000] bf16(h)   -> 3,200,000 units
#define CNT64_OFF  3200000    // u64[50,000]                 -> 100,000 units
#define DINV_OFF   3300000    // float[50,000]
#define WB_OFF     3352000    // ushort[16,384]
#define GSTART_OFF 3362000    // int[129]
#define ROWS_OFF   3363000    // int[50,001]
#define BSUM_OFF   3414000    // int[256]
#define EPACK_OFF  3414100    // u64[625,000] (even offset)  -> 1,250,000 units
#define SLOT_OFF   4664100    // u32[625,000]
#define TMP_OFF    5289104    // ushort[6,400,000] (16B-aligned) -> 3,200,000 units
// end 8,489,104 * 4B = 34.0 MB? > 31.4 prior max... keep TMP overlay-free but trim:
// SLOT is dead after csr_fill; TMP may start at SLOT_OFF (16B aligned: 4,664,100*4=18,656,400, /16 ok)
#undef TMP_OFF
#define TMP_OFF    4664100    // overlays SLOT + tail; ends 7,864,100 units = 31.5 MB? slot 625,000 < 3,200,000 so TMP spills past; end 7,864,100*4 = 31.46 MB (prior runs used 31.4 MB OK)

// ---------------- prep: zero cnt64 + convert W -> bf16 ----------------
__global__ void prep(const float* __restrict__ W, unsigned short* __restrict__ wb,
                     uint4* __restrict__ cntz) {
    int i = blockIdx.x * 256 + threadIdx.x;
    if (i < 100000 / 4) cntz[i] = make_uint4(0u, 0u, 0u, 0u);
    if (i < HIDDEN * HIDDEN) wb[i] = f2b(W[i]);
}

// ---------------- fused: GEMM tiles + edge histogram (8 edges/thread) ----------------
__global__ __launch_bounds__(256) void gemm_hist(const float* __restrict__ x,
                                                 const unsigned short* __restrict__ wb,
                                                 unsigned short* __restrict__ hb,
                                                 const int* __restrict__ dst,
                                                 const float* __restrict__ w,
                                                 u64* __restrict__ cnt64,
                                                 unsigned int* __restrict__ slot) {
    if (blockIdx.x >= NGEMM_BLK) {
        int base = (blockIdx.x - NGEMM_BLK) * 256 + threadIdx.x;   // 8-edge group id
        if (base * 8 >= N_EDGES) return;
        int4   dA = ((const int4*)dst)[base * 2];
        int4   dB = ((const int4*)dst)[base * 2 + 1];
        float4 wA = ((const float4*)w)[base * 2];
        float4 wB = ((const float4*)w)[base * 2 + 1];
        uint4 sA, sB;
        {
            unsigned int fx = (unsigned int)(wA.x * FIXSCALE + 0.5f);
            sA.x = (unsigned int)(atomicAdd(&cnt64[dA.x], (1ULL << 32) | (u64)fx) >> 32);
            fx = (unsigned int)(wA.y * FIXSCALE + 0.5f);
            sA.y = (unsigned int)(atomicAdd(&cnt64[dA.y], (1ULL << 32) | (u64)fx) >> 32);
            fx = (unsigned int)(wA.z * FIXSCALE + 0.5f);
            sA.z = (unsigned int)(atomicAdd(&cnt64[dA.z], (1ULL << 32) | (u64)fx) >> 32);
            fx = (unsigned int)(wA.w * FIXSCALE + 0.5f);
            sA.w = (unsigned int)(atomicAdd(&cnt64[dA.w], (1ULL << 32) | (u64)fx) >> 32);
            fx = (unsigned int)(wB.x * FIXSCALE + 0.5f);
            sB.x = (unsigned int)(atomicAdd(&cnt64[dB.x], (1ULL << 32) | (u64)fx) >> 32);
            fx = (unsigned int)(wB.y * FIXSCALE + 0.5f);
            sB.y = (unsigned int)(atomicAdd(&cnt64[dB.y], (1ULL << 32) | (u64)fx) >> 32);
            fx = (unsigned int)(wB.z * FIXSCALE + 0.5f);
            sB.z = (unsigned int)(atomicAdd(&cnt64[dB.z], (1ULL << 32) | (u64)fx) >> 32);
            fx = (unsigned int)(wB.w * FIXSCALE + 0.5f);
            sB.w = (unsigned int)(atomicAdd(&cnt64[dB.w], (1ULL << 32) | (u64)fx) >> 32);
        }
        ((uint4*)slot)[base * 2]     = sA;
        ((uint4*)slot)[base * 2 + 1] = sB;
        return;
    }
    // ---- GEMM part: h = x @ W.T ----
    const int wave = threadIdx.x >> 6;
    const int lane = threadIdx.x & 63;
    const int row0 = blockIdx.x * 64 + wave * 16;
    const int r  = lane & 15;
    const int ko = (lane >> 4) * 8;
    f32x4 acc[8];
#pragma unroll
    for (int t = 0; t < 8; ++t) { acc[t][0] = 0.f; acc[t][1] = 0.f; acc[t][2] = 0.f; acc[t][3] = 0.f; }
    int arow = row0 + r;
    if (arow >= N_NODES) arow = N_NODES - 1;
    const size_t abase = (size_t)arow * HIDDEN + ko;
#pragma unroll
    for (int kt = 0; kt < HIDDEN; kt += 32) {
        float4 a0 = *(const float4*)(x + abase + kt);
        float4 a1 = *(const float4*)(x + abase + kt + 4);
        bf16x8 a;
        a[0] = (__bf16)a0.x; a[1] = (__bf16)a0.y; a[2] = (__bf16)a0.z; a[3] = (__bf16)a0.w;
        a[4] = (__bf16)a1.x; a[5] = (__bf16)a1.y; a[6] = (__bf16)a1.z; a[7] = (__bf16)a1.w;
#pragma unroll
        for (int t = 0; t < 8; ++t) {
            bf16x8 b = *(const bf16x8*)(wb + (size_t)(t * 16 + r) * HIDDEN + kt + ko);
            acc[t] = __builtin_amdgcn_mfma_f32_16x16x32_bf16(a, b, acc[t], 0, 0, 0);
        }
    }
    const int orow = row0 + (lane >> 4) * 4;
#pragma unroll
    for (int t = 0; t < 8; ++t) {
#pragma unroll
        for (int j = 0; j < 4; ++j) {
            int rr = orow + j;
            if (rr < N_NODES) hb[(size_t)rr * HIDDEN + t * 16 + r] = f2b(acc[t][j]);
        }
    }
}

// ---------------- scan partials + dinv + graph bounds (fused) ----------------
__global__ void scan_partial(const u64* __restrict__ cnt64, int* __restrict__ bsum,
                             float* __restrict__ dinv,
                             const int* __restrict__ batch, int* __restrict__ gstart) {
    __shared__ int red[256];
    int i = blockIdx.x * 256 + threadIdx.x;
    int c = 0;
    if (i < N_NODES) {
        u64 v = cnt64[i];
        c = (int)(v >> 32);
        dinv[i] = rsqrtf(1.0f + (float)(unsigned int)v * (1.0f / FIXSCALE));
        int b0 = batch[i];
        int prev = (i == 0) ? -1 : batch[i - 1];
        for (int g = prev + 1; g <= b0; ++g) gstart[g] = i;
        if (i == N_NODES - 1) {
            for (int g = b0 + 1; g <= NUM_GRAPHS; ++g) gstart[g] = N_NODES;
        }
    }
    red[threadIdx.x] = c;
    __syncthreads();
    for (int off = 128; off > 0; off >>= 1) {
        if (threadIdx.x < off) red[threadIdx.x] += red[threadIdx.x + off];
        __syncthreads();
    }
    if (threadIdx.x == 0) bsum[blockIdx.x] = red[0];
}

// ---------------- scan_emit with inlined block-offset scan (drops scan_bsums) ----------------
__global__ void scan_emit(const u64* __restrict__ cnt64, const int* __restrict__ bsum,
                          int* __restrict__ rowstart) {
    __shared__ int sb[256];
    __shared__ int s[256];
    int t = threadIdx.x;
    // block-offset: inclusive scan of bsum in LDS, exclusive at our block
    sb[t] = (t < NB_SCAN) ? bsum[t] : 0;
    __syncthreads();
    for (int off = 1; off < 256; off <<= 1) {
        int v = (t >= off) ? sb[t - off] : 0;
        __syncthreads();
        sb[t] += v;
        __syncthreads();
    }
    int boff = (blockIdx.x == 0) ? 0 : sb[blockIdx.x - 1];
    // local exclusive scan of this block's counts
    int i = blockIdx.x * 256 + t;
    int v0 = (i < N_NODES) ? (int)(cnt64[i] >> 32) : 0;
    s[t] = v0;
    __syncthreads();
    for (int off = 1; off < 256; off <<= 1) {
        int v = (t >= off) ? s[t - off] : 0;
        __syncthreads();
        s[t] += v;
        __syncthreads();
    }
    if (i < N_NODES) rowstart[i] = boff + s[t] - v0;
    if (i == N_NODES) rowstart[N_NODES] = N_EDGES;
}

// ---------------- fill CSR: atomic-free, 4 edges/thread ----------------
__global__ void csr_fill(const int* __restrict__ src, const int* __restrict__ dst,
                         const float* __restrict__ w, const float* __restrict__ dinv,
                         const int* __restrict__ rowstart, const unsigned int* __restrict__ slot,
                         u64* __restrict__ epack) {
    int base = blockIdx.x * blockDim.x + threadIdx.x;
    if (base * 4 >= N_EDGES) return;
    int4   s4 = ((const int4*)src)[base];
    int4   d4 = ((const int4*)dst)[base];
    float4 w4 = ((const float4*)w)[base];
    uint4  r4 = ((const uint4*)slot)[base];
    float nm0 = dinv[s4.x] * w4.x * dinv[d4.x];
    float nm1 = dinv[s4.y] * w4.y * dinv[d4.y];
    float nm2 = dinv[s4.z] * w4.z * dinv[d4.z];
    float nm3 = dinv[s4.w] * w4.w * dinv[d4.w];
    epack[rowstart[d4.x] + (int)r4.x] = (u64)(unsigned int)s4.x | ((u64)__float_as_uint(nm0) << 32);
    epack[rowstart[d4.y] + (int)r4.y] = (u64)(unsigned int)s4.y | ((u64)__float_as_uint(nm1) << 32);
    epack[rowstart[d4.z] + (int)r4.z] = (u64)(unsigned int)s4.z | ((u64)__float_as_uint(nm2) << 32);
    epack[rowstart[d4.w] + (int)r4.w] = (u64)(unsigned int)s4.w | ((u64)__float_as_uint(nm3) << 32);
}

// ---------------- gather: 16 lanes/node, 4-edge unroll, writes bf16 tmp ----------------
__global__ __launch_bounds__(256) void gather_fused(const unsigned short* __restrict__ hb,
                                                    const int* __restrict__ rowstart,
                                                    const u64* __restrict__ epack,
                                                    const float* __restrict__ dinv,
                                                    const float* __restrict__ b,
                                                    unsigned short* __restrict__ tmp) {
    const int t = threadIdx.x;
    const int n = blockIdx.x * 16 + (t >> 4);
    if (n >= N_NODES) return;
    const int c8 = (t & 15) * 8;
    const int s0 = rowstart[n];
    const int e0 = rowstart[n + 1];
    const float di = dinv[n];
    const float sl = di * di;
    float acc[8];
    {
        u16x8 hv = *(const u16x8*)(hb + (size_t)n * HIDDEN + c8);
#pragma unroll
        for (int j = 0; j < 8; ++j) acc[j] = sl * b2f(hv[j]);
    }
    int p = s0;
    for (; p + 4 <= e0; p += 4) {
        u64 e1 = epack[p];
        u64 e2 = epack[p + 1];
        u64 e3 = epack[p + 2];
        u64 e4 = epack[p + 3];
        int   x1 = (int)(unsigned int)e1;
        int   x2 = (int)(unsigned int)e2;
        int   x3 = (int)(unsigned int)e3;
        int   x4 = (int)(unsigned int)e4;
        float n1 = __uint_as_float((unsigned int)(e1 >> 32));
        float n2 = __uint_as_float((unsigned int)(e2 >> 32));
        float n3 = __uint_as_float((unsigned int)(e3 >> 32));
        float n4 = __uint_as_float((unsigned int)(e4 >> 32));
        u16x8 v1 = *(const u16x8*)(hb + (size_t)x1 * HIDDEN + c8);
        u16x8 v2 = *(const u16x8*)(hb + (size_t)x2 * HIDDEN + c8);
        u16x8 v3 = *(const u16x8*)(hb + (size_t)x3 * HIDDEN + c8);
        u16x8 v4 = *(const u16x8*)(hb + (size_t)x4 * HIDDEN + c8);
#pragma unroll
        for (int j = 0; j < 8; ++j) acc[j] = fmaf(n1, b2f(v1[j]), acc[j]);
#pragma unroll
        for (int j = 0; j < 8; ++j) acc[j] = fmaf(n2, b2f(v2[j]), acc[j]);
#pragma unroll
        for (int j = 0; j < 8; ++j) acc[j] = fmaf(n3, b2f(v3[j]), acc[j]);
#pragma unroll
        for (int j = 0; j < 8; ++j) acc[j] = fmaf(n4, b2f(v4[j]), acc[j]);
    }
    for (; p < e0; ++p) {
        u64 e1 = epack[p];
        int   x1 = (int)(unsigned int)e1;
        float n1 = __uint_as_float((unsigned int)(e1 >> 32));
        u16x8 v1 = *(const u16x8*)(hb + (size_t)x1 * HIDDEN + c8);
#pragma unroll
        for (int j = 0; j < 8; ++j) acc[j] = fmaf(n1, b2f(v1[j]), acc[j]);
    }
    float4 b0 = *(const float4*)(b + c8);
    float4 b1 = *(const float4*)(b + c8 + 4);
    u16x8 o;
    o[0] = f2b(acc[0] + b0.x); o[1] = f2b(acc[1] + b0.y);
    o[2] = f2b(acc[2] + b0.z); o[3] = f2b(acc[3] + b0.w);
    o[4] = f2b(acc[4] + b1.x); o[5] = f2b(acc[5] + b1.y);
    o[6] = f2b(acc[6] + b1.z); o[7] = f2b(acc[7] + b1.w);
    *(u16x8*)(tmp + (size_t)n * HIDDEN + c8) = o;
}

// ---------------- fused per-graph stats + normalize + relu ----------------
__global__ __launch_bounds__(256) void stats_apply(const unsigned short* __restrict__ tmp,
                                                   const int* __restrict__ gstart,
                                                   const float* __restrict__ ms,
                                                   const float* __restrict__ gw,
                                                   const float* __restrict__ gb,
                                                   float* __restrict__ out) {
    const int g = blockIdx.x >> 2;
    const int q = blockIdx.x & 3;
    const int l = threadIdx.x & 31;
    const int c = q * 32 + l;
    const int r = threadIdx.x >> 5;
    const int s = gstart[g];
    const int e = gstart[g + 1];
    float sum = 0.f, sq = 0.f;
    for (int n = s + r; n < e; n += 8) {
        float v = b2f(tmp[(size_t)n * HIDDEN + c]);
        sum += v;
        sq = fmaf(v, v, sq);
    }
    __shared__ float ssum[8][32], ssq[8][32];
    __shared__ float sA[32], sS[32];
    ssum[r][l] = sum;
    ssq[r][l]  = sq;
    __syncthreads();
    if (r == 0) {
#pragma unroll
        for (int i = 1; i < 8; ++i) { sum += ssum[i][l]; sq += ssq[i][l]; }
        float cnt  = (float)max(e - s, 1);
        float mean = sum / cnt;
        float m2   = sq / cnt;
        float msv  = ms[c];
        float var  = fmaxf(m2 - mean * mean * msv * (2.f - msv), 0.f);
        float a    = gw[c] * rsqrtf(var + EPS_GN);
        sA[l] = a;
        sS[l] = gb[c] - a * msv * mean;
    }
    __syncthreads();
    float a  = sA[l];
    float sh = sS[l];
    for (int n = s + r; n < e; n += 8) {
        float v = b2f(tmp[(size_t)n * HIDDEN + c]);
        out[(size_t)n * HIDDEN + c] = fmaxf(fmaf(a, v, sh), 0.f);
    }
}

extern "C" void kernel_launch(void* const* d_in, const int* in_sizes, int n_in,
                              void* d_out, int out_size, void* d_ws, size_t ws_size,
                              hipStream_t stream) {
    const float* node  = (const float*)d_in[0];
    const int*   ei    = (const int*)d_in[1];
    const float* eattr = (const float*)d_in[2];
    const int*   batch = (const int*)d_in[3];
    const float* W     = (const float*)d_in[4];
    const float* b     = (const float*)d_in[5];
    const float* gnw   = (const float*)d_in[6];
    const float* gnb   = (const float*)d_in[7];
    const float* gnms  = (const float*)d_in[8];
    float* out = (float*)d_out;
    float* ws  = (float*)d_ws;

    const int* src = ei;
    const int* dst = ei + N_EDGES;

    unsigned short* hb = (unsigned short*)(ws + HB_OFF);
    u64*   cnt64   = (u64*)(ws + CNT64_OFF);
    float* dinv    = ws + DINV_OFF;
    unsigned short* wb = (unsigned short*)(ws + WB_OFF);
    int*   gstart  = (int*)(ws + GSTART_OFF);
    int*   rowstart= (int*)(ws + ROWS_OFF);
    int*   bsum    = (int*)(ws + BSUM_OFF);
    u64*   epack   = (u64*)(ws + EPACK_OFF);
    unsigned int* slot = (unsigned int*)(ws + SLOT_OFF);
    unsigned short* tmp = (unsigned short*)(ws + TMP_OFF);   // overlays slot (dead after csr_fill)

    prep<<<98, 256, 0, stream>>>(W, wb, (uint4*)cnt64);
    gemm_hist<<<NGEMM_BLK + NHIST_BLK, 256, 0, stream>>>(node, wb, hb, dst, eattr, cnt64, slot);
    scan_partial<<<NB_SCAN, 256, 0, stream>>>(cnt64, bsum, dinv, batch, gstart);
    scan_emit<<<NB_SCAN, 256, 0, stream>>>(cnt64, bsum, rowstart);
    csr_fill<<<(N_EDGES / 4 + 255) / 256, 256, 0, stream>>>(src, dst, eattr, dinv, rowstart, slot, epack);
    gather_fused<<<(N_NODES + 15) / 16, 256, 0, stream>>>(hb, rowstart, epack, dinv, b, tmp);
    stats_apply<<<NUM_GRAPHS * 4, 256, 0, stream>>>(tmp, gstart, gnms, gnw, gnb, out);

    (void)in_sizes; (void)n_in; (void)out_size; (void)ws_size;
}